// Round 1
// baseline (7235.007 us; speedup 1.0000x reference)
//
#include <hip/hip_runtime.h>
#include <hip/hip_bf16.h>

#define B_ 32
#define T_ 64
#define STOCH_ 1024
#define DETER_ 4096
#define HID_ 1024
#define EMB_ 1536
#define ACTD_ 128
#define GRUK 5120
#define GRUN 12288
#define KC 512
#define LDAP (KC + 8)   // padded LDS row stride (elements) -> 2-way bank aliasing (free)

typedef __attribute__((ext_vector_type(8))) __bf16 bf16x8;
typedef __attribute__((ext_vector_type(4))) float f32x4;
typedef __attribute__((ext_vector_type(8))) unsigned short u16x8;
typedef __attribute__((ext_vector_type(4))) unsigned short u16x4;

__device__ inline unsigned short f2bf(float f) {
    union { float f; unsigned u; } x; x.f = f;
    unsigned r = x.u + 0x7fffu + ((x.u >> 16) & 1u);
    return (unsigned short)(r >> 16);
}
__device__ inline float sigmoidf_(float v) { return 1.f / (1.f + __expf(-v)); }
__device__ inline float siluf_(float v)    { return v / (1.f + __expf(-v)); }
__device__ inline float softplusf_(float v){ return fmaxf(v, 0.f) + __logf(1.f + __expf(-fabsf(v))); }

// ---------------- prep kernels ----------------

// Pack W[K,N] (fp32 row-major) into MFMA B-frag-linear bf16:
// dst[((n_t*(K/32)+k_t)*64 + lane)*8 + i] = bf16(W[k_t*32+(lane>>4)*8+i, n_t*16+(lane&15)])
__global__ __launch_bounds__(256) void k_pack(const float* __restrict__ W,
                                              unsigned short* __restrict__ dst,
                                              int K, int N) {
    long fid = (long)blockIdx.x * 256 + threadIdx.x;
    long nfr = (long)K * N / 8;
    if (fid >= nfr) return;
    int lane = (int)(fid & 63);
    long tile = fid >> 6;
    int ktiles = K >> 5;
    int k_t = (int)(tile % ktiles);
    int n_t = (int)(tile / ktiles);
    int c = lane & 15, kb = lane >> 4;
    int k0 = k_t * 32 + kb * 8;
    int n = n_t * 16 + c;
    unsigned short v[8];
#pragma unroll
    for (int i = 0; i < 8; i++) v[i] = f2bf(W[(long)(k0 + i) * N + n]);
    *reinterpret_cast<u16x8*>(dst + fid * 8) = *reinterpret_cast<u16x8*>(v);
}

__global__ __launch_bounds__(256) void k_conv(const float* __restrict__ s,
                                              unsigned short* __restrict__ d, long n) {
    long i = ((long)blockIdx.x * 256 + threadIdx.x) * 4;
    if (i >= n) return;
    f32x4 v = *reinterpret_cast<const f32x4*>(s + i);
    unsigned short o[4];
#pragma unroll
    for (int k = 0; k < 4; k++) o[k] = f2bf(v[k]);
    *reinterpret_cast<u16x4*>(d + i) = *reinterpret_cast<u16x4*>(o);
}

__global__ __launch_bounds__(256) void k_copy(const float* __restrict__ s,
                                              float* __restrict__ d, long n) {
    long i = ((long)blockIdx.x * 256 + threadIdx.x) * 4;
    if (i >= n) return;
    *reinterpret_cast<f32x4*>(d + i) = *reinterpret_cast<const f32x4*>(s + i);
}

// ---------------- GEMM building blocks ----------------

// reduce per-slab (sum,sumsq) partials -> per-row mean / rstd in LDS
__device__ inline void ln_stats_prologue(const float* __restrict__ partials, int nslab,
                                         float invN, float* s_mean, float* s_rstd) {
    if (threadIdx.x < 32) {
        int r = threadIdx.x;
        float s = 0.f, q = 0.f;
        for (int j = 0; j < nslab; j++) {
            s += partials[((long)j * 32 + r) * 2];
            q += partials[((long)j * 32 + r) * 2 + 1];
        }
        float m = s * invN;
        float var = q * invN - m * m;
        s_mean[r] = m;
        s_rstd[r] = rsqrtf(var + 1e-3f);
    }
    __syncthreads();
}

__device__ inline void stage_bf16(unsigned short* __restrict__ lds_a,
                                  const unsigned short* __restrict__ src,
                                  int lda, int k0, int cw) {
    for (int e = (int)threadIdx.x * 8; e < 32 * cw; e += 256 * 8) {
        int row = e / cw, col = e - row * cw;
        *reinterpret_cast<u16x8*>(&lds_a[row * LDAP + col]) =
            *reinterpret_cast<const u16x8*>(&src[(long)row * lda + k0 + col]);
    }
}

// stage LN(raw)*g+b -> SiLU -> bf16 into LDS (x / h finalization fused into consumer)
__device__ inline void stage_lnsilu(unsigned short* __restrict__ lds_a,
                                    const float* __restrict__ raw, int ldr, int colbase,
                                    int k0, int cw,
                                    const float* __restrict__ g, const float* __restrict__ b,
                                    const float* s_mean, const float* s_rstd) {
    for (int e = (int)threadIdx.x * 8; e < 32 * cw; e += 256 * 8) {
        int row = e / cw, col = e - row * cw;
        int kg = k0 + col;
        float m = s_mean[row], rs = s_rstd[row];
        const float* sp = &raw[(long)row * ldr + colbase + kg];
        unsigned short v[8];
#pragma unroll
        for (int i = 0; i < 8; i++) {
            float ln = (sp[i] - m) * rs * g[kg + i] + b[kg + i];
            v[i] = f2bf(siluf_(ln));
        }
        *reinterpret_cast<u16x8*>(&lds_a[row * LDAP + col]) = *reinterpret_cast<u16x8*>(v);
    }
}

// 16x16x32 MFMA over one staged chunk; wave computes 32 rows x 16 cols (ntile)
__device__ inline void mfma_chunk(const unsigned short* __restrict__ lds_a,
                                  const unsigned short* __restrict__ Bp,
                                  int ntile, long Ktiles, long kt0, int nkt,
                                  int lane, f32x4& acc0, f32x4& acc1) {
    int c = lane & 15, kb = lane >> 4;
    const unsigned short* a0p = &lds_a[c * LDAP + kb * 8];
    const unsigned short* a1p = &lds_a[(16 + c) * LDAP + kb * 8];
    const unsigned short* bp = Bp + ((long)ntile * Ktiles + kt0) * 512 + lane * 8;
    for (int kt = 0; kt < nkt; ++kt) {
        bf16x8 a0 = *reinterpret_cast<const bf16x8*>(a0p + kt * 32);
        bf16x8 a1 = *reinterpret_cast<const bf16x8*>(a1p + kt * 32);
        bf16x8 bv = *reinterpret_cast<const bf16x8*>(bp + (long)kt * 512);
        acc0 = __builtin_amdgcn_mfma_f32_16x16x32_bf16(a0, bv, acc0, 0, 0, 0);
        acc1 = __builtin_amdgcn_mfma_f32_16x16x32_bf16(a1, bv, acc1, 0, 0, 0);
    }
}

__device__ inline void acc_to_lds(float (*s_out)[66], int wave, int lane,
                                  const f32x4& acc0, const f32x4& acc1) {
    int c = lane & 15, rb = lane >> 4;
#pragma unroll
    for (int j = 0; j < 4; j++) {
        s_out[rb * 4 + j][wave * 16 + c] = acc0[j];
        s_out[16 + rb * 4 + j][wave * 16 + c] = acc1[j];
    }
}

// raw epilogue: +addin, write fp32 raw, per-slab LN partials
__device__ inline void epi_raw(float (*s_out)[66],
                               const float* __restrict__ addin, long addin_ld, int n0_add,
                               float* __restrict__ outp, long out_ld, int n0_out,
                               float* __restrict__ partials, int slab) {
    int row = threadIdx.x >> 3, c8 = (threadIdx.x & 7) * 8;
    float vals[8];
#pragma unroll
    for (int i = 0; i < 8; i++) {
        float v = s_out[row][c8 + i];
        if (addin) v += addin[(long)row * addin_ld + n0_add + c8 + i];
        vals[i] = v;
        s_out[row][c8 + i] = v;
    }
#pragma unroll
    for (int i = 0; i < 8; i++) outp[(long)row * out_ld + n0_out + c8 + i] = vals[i];
    __syncthreads();
    if (threadIdx.x < 32) {
        float s = 0.f, q = 0.f;
        for (int j = 0; j < 64; j++) { float v = s_out[threadIdx.x][j]; s += v; q += v * v; }
        partials[((long)slab * 32 + threadIdx.x) * 2] = s;
        partials[((long)slab * 32 + threadIdx.x) * 2 + 1] = q;
    }
}

// ---------------- per-step kernels ----------------

// L1: x_raw = stoch_bf16 @ Win_s + A_pre[t]   (N=1024, K=1024), partials px
__global__ __launch_bounds__(256) void k_x(const unsigned short* __restrict__ Bp,
                                           const unsigned short* __restrict__ stoch_bf16,
                                           const float* __restrict__ A_pre_t,
                                           float* __restrict__ x_raw, float* __restrict__ px) {
    __shared__ __align__(16) unsigned short lds_a[32 * LDAP];
    __shared__ float s_out[32][66];
    int wave = threadIdx.x >> 6, lane = threadIdx.x & 63;
    int ntile = blockIdx.x * 4 + wave;
    f32x4 acc0 = {0.f, 0.f, 0.f, 0.f}, acc1 = {0.f, 0.f, 0.f, 0.f};
    for (int ch = 0; ch < 2; ++ch) {
        __syncthreads();
        stage_bf16(lds_a, stoch_bf16, STOCH_, ch * KC, KC);
        __syncthreads();
        mfma_chunk(lds_a, Bp, ntile, 32, ch * 16, 16, lane, acc0, acc1);
    }
    __syncthreads();
    acc_to_lds(s_out, wave, lane, acc0, acc1);
    __syncthreads();
    epi_raw(s_out, A_pre_t, (long)T_ * 1024, blockIdx.x * 64,
            x_raw, 1024, blockIdx.x * 64, px, blockIdx.x);
}

// L2a: G_raw = [LN+SiLU(x_raw) | deter_bf16] @ Wgru  (N=12288, K=5120), partials pg
__global__ __launch_bounds__(256) void k_gru(const unsigned short* __restrict__ Bp,
                                             const float* __restrict__ x_raw,
                                             const float* __restrict__ px,
                                             const float* __restrict__ g_in,
                                             const float* __restrict__ b_in,
                                             const unsigned short* __restrict__ deter_bf16,
                                             float* __restrict__ G_raw, float* __restrict__ pg) {
    __shared__ __align__(16) unsigned short lds_a[32 * LDAP];
    __shared__ float s_out[32][66];
    __shared__ float s_mean[32], s_rstd[32];
    ln_stats_prologue(px, 16, 1.f / 1024.f, s_mean, s_rstd);
    int wave = threadIdx.x >> 6, lane = threadIdx.x & 63;
    int ntile = blockIdx.x * 4 + wave;
    f32x4 acc0 = {0.f, 0.f, 0.f, 0.f}, acc1 = {0.f, 0.f, 0.f, 0.f};
    for (int ch = 0; ch < 10; ++ch) {
        __syncthreads();
        if (ch < 2) stage_lnsilu(lds_a, x_raw, 1024, 0, ch * KC, KC, g_in, b_in, s_mean, s_rstd);
        else        stage_bf16(lds_a, deter_bf16, DETER_, ch * KC - 1024, KC);
        __syncthreads();
        mfma_chunk(lds_a, Bp, ntile, 160, ch * 16, 16, lane, acc0, acc1);
    }
    __syncthreads();
    acc_to_lds(s_out, wave, lane, acc0, acc1);
    __syncthreads();
    epi_raw(s_out, nullptr, 0, 0, G_raw, GRUN, blockIdx.x * 64, pg, blockIdx.x);
}

// L2b: LN(G)+gates -> deter (fp32 + bf16), write out[:,t,0:4096]
__global__ __launch_bounds__(256) void k_deter(const float* __restrict__ G_raw,
                                               const float* __restrict__ pg,
                                               const float* __restrict__ g_gru,
                                               const float* __restrict__ b_gru,
                                               float* __restrict__ deter_f32,
                                               unsigned short* __restrict__ deter_bf16,
                                               float* __restrict__ out, int t) {
    __shared__ float s_mean[32], s_rstd[32];
    ln_stats_prologue(pg, 192, 1.f / 12288.f, s_mean, s_rstd);
    int eid = blockIdx.x * 256 + threadIdx.x;   // 32768 threads * 4 elems
    int b = eid >> 10;
    int j = (eid & 1023) * 4;
    const float* gr = G_raw + (long)b * GRUN;
    f32x4 r4 = *reinterpret_cast<const f32x4*>(gr + j);
    f32x4 c4 = *reinterpret_cast<const f32x4*>(gr + 4096 + j);
    f32x4 u4 = *reinterpret_cast<const f32x4*>(gr + 8192 + j);
    f32x4 d4 = *reinterpret_cast<const f32x4*>(deter_f32 + (long)b * DETER_ + j);
    float m = s_mean[b], rs = s_rstd[b];
    f32x4 nd;
    unsigned short db[4];
#pragma unroll
    for (int i = 0; i < 4; i++) {
        float lr = (r4[i] - m) * rs * g_gru[j + i] + b_gru[j + i];
        float lc = (c4[i] - m) * rs * g_gru[4096 + j + i] + b_gru[4096 + j + i];
        float lu = (u4[i] - m) * rs * g_gru[8192 + j + i] + b_gru[8192 + j + i];
        float reset = sigmoidf_(lr);
        float cand = tanhf(reset * lc);
        float upd = sigmoidf_(lu - 1.f);
        float dn = upd * cand + (1.f - upd) * d4[i];
        nd[i] = dn; db[i] = f2bf(dn);
    }
    *reinterpret_cast<f32x4*>(deter_f32 + (long)b * DETER_ + j) = nd;
    *reinterpret_cast<u16x4*>(deter_bf16 + (long)b * DETER_ + j) = *reinterpret_cast<u16x4*>(db);
    *reinterpret_cast<f32x4*>(out + ((long)(b * T_ + t)) * 10240 + j) = nd;
}

// L3: h_raw[:,0:1024] = deter@Wio ; h_raw[:,1024:2048] = deter@Wood + E_pre[t]; partials ph
__global__ __launch_bounds__(256) void k_h(const unsigned short* __restrict__ Wio,
                                           const unsigned short* __restrict__ Wood,
                                           const unsigned short* __restrict__ deter_bf16,
                                           const float* __restrict__ E_pre_t,
                                           float* __restrict__ h_raw, float* __restrict__ ph) {
    __shared__ __align__(16) unsigned short lds_a[32 * LDAP];
    __shared__ float s_out[32][66];
    int p = blockIdx.x < 16;
    int bi = blockIdx.x & 15;
    const unsigned short* Bp = p ? Wio : Wood;
    int wave = threadIdx.x >> 6, lane = threadIdx.x & 63;
    int ntile = bi * 4 + wave;
    f32x4 acc0 = {0.f, 0.f, 0.f, 0.f}, acc1 = {0.f, 0.f, 0.f, 0.f};
    for (int ch = 0; ch < 8; ++ch) {
        __syncthreads();
        stage_bf16(lds_a, deter_bf16, DETER_, ch * KC, KC);
        __syncthreads();
        mfma_chunk(lds_a, Bp, ntile, 128, ch * 16, 16, lane, acc0, acc1);
    }
    __syncthreads();
    acc_to_lds(s_out, wave, lane, acc0, acc1);
    __syncthreads();
    epi_raw(s_out, p ? nullptr : E_pre_t, (long)T_ * 1024, bi * 64,
            h_raw, 2048, (p ? 0 : 1024) + bi * 64, ph, blockIdx.x);
}

// L4: stats = LN+SiLU(h) @ W + b; softplus; sample; write outputs (+stoch_bf16 for q)
__global__ __launch_bounds__(256) void k_stats(const unsigned short* __restrict__ Wims,
                                               const unsigned short* __restrict__ Wobs,
                                               const float* __restrict__ h_raw,
                                               const float* __restrict__ ph,
                                               const float* __restrict__ g_io,
                                               const float* __restrict__ b_io,
                                               const float* __restrict__ g_oo,
                                               const float* __restrict__ b_oo,
                                               const float* __restrict__ b_ims,
                                               const float* __restrict__ b_obs,
                                               const float* __restrict__ noise_p,
                                               const float* __restrict__ noise_q,
                                               float* __restrict__ out,
                                               unsigned short* __restrict__ stoch_bf16, int t) {
    __shared__ __align__(16) unsigned short lds_a[32 * LDAP];
    __shared__ float s_out[32][66];
    __shared__ float s_mean[32], s_rstd[32];
    int q = blockIdx.x >= 32;
    int s = blockIdx.x & 31;
    ln_stats_prologue(ph + (q ? 16 * 32 * 2 : 0), 16, 1.f / 1024.f, s_mean, s_rstd);
    const unsigned short* Bp = q ? Wobs : Wims;
    const float* g = q ? g_oo : g_io;
    const float* bb = q ? b_oo : b_io;
    const float* bias = q ? b_obs : b_ims;
    int colbase = q ? 1024 : 0;
    int wave = threadIdx.x >> 6, lane = threadIdx.x & 63;
    int ntile = (wave < 2) ? (s * 2 + wave) : (64 + s * 2 + (wave - 2));
    f32x4 acc0 = {0.f, 0.f, 0.f, 0.f}, acc1 = {0.f, 0.f, 0.f, 0.f};
    for (int ch = 0; ch < 2; ++ch) {
        __syncthreads();
        stage_lnsilu(lds_a, h_raw, 2048, colbase, ch * KC, KC, g, bb, s_mean, s_rstd);
        __syncthreads();
        mfma_chunk(lds_a, Bp, ntile, 32, ch * 16, 16, lane, acc0, acc1);
    }
    __syncthreads();
    int c = lane & 15, rb = lane >> 4;
    float bv = bias[ntile * 16 + c];
#pragma unroll
    for (int j = 0; j < 4; j++) {
        s_out[rb * 4 + j][wave * 16 + c] = acc0[j] + bv;
        s_out[16 + rb * 4 + j][wave * 16 + c] = acc1[j] + bv;
    }
    __syncthreads();
    int r = threadIdx.x >> 3, j0 = (threadIdx.x & 7) * 4;
    const float* noise = q ? noise_q : noise_p;
#pragma unroll
    for (int i = 0; i < 4; i++) {
        int jj = j0 + i;
        float mean = s_out[r][jj];
        float sv = s_out[r][32 + jj];
        float sd = softplusf_(sv) + 0.1f;
        int cg = s * 32 + jj;
        float nz = noise[((long)(r * T_ + t)) * 1024 + cg];
        float st = mean + sd * nz;
        float* orow = out + ((long)(r * T_ + t)) * 10240;
        if (q) {
            orow[4096 + cg] = st; orow[5120 + cg] = mean; orow[6144 + cg] = sd;
            stoch_bf16[(long)r * 1024 + cg] = f2bf(st);
        } else {
            orow[7168 + cg] = st; orow[8192 + cg] = mean; orow[9216 + cg] = sd;
        }
    }
}

// prep GEMM for A_pre / E_pre: out[M,1024] = A[M,K]_bf16 @ Bp ; grid (16, M/32)
__global__ __launch_bounds__(256) void k_prepgemm(const unsigned short* __restrict__ A, int K,
                                                  const unsigned short* __restrict__ Bp,
                                                  float* __restrict__ outp) {
    __shared__ __align__(16) unsigned short lds_a[32 * LDAP];
    __shared__ float s_out[32][66];
    int wave = threadIdx.x >> 6, lane = threadIdx.x & 63;
    int ntile = blockIdx.x * 4 + wave;
    int m0 = blockIdx.y * 32;
    int Ktiles = K >> 5;
    f32x4 acc0 = {0.f, 0.f, 0.f, 0.f}, acc1 = {0.f, 0.f, 0.f, 0.f};
    int nch = (K + KC - 1) / KC;
    for (int ch = 0; ch < nch; ++ch) {
        int cw = K - ch * KC; if (cw > KC) cw = KC;
        __syncthreads();
        stage_bf16(lds_a, A + (long)m0 * K, K, ch * KC, cw);
        __syncthreads();
        mfma_chunk(lds_a, Bp, ntile, Ktiles, ch * 16, cw >> 5, lane, acc0, acc1);
    }
    __syncthreads();
    acc_to_lds(s_out, wave, lane, acc0, acc1);
    __syncthreads();
    int row = threadIdx.x >> 3, c8 = (threadIdx.x & 7) * 8;
#pragma unroll
    for (int i = 0; i < 8; i++)
        outp[(long)(m0 + row) * 1024 + blockIdx.x * 64 + c8 + i] = s_out[row][c8 + i];
}

// ---------------- host ----------------

extern "C" void kernel_launch(void* const* d_in, const int* in_sizes, int n_in,
                              void* d_out, int out_size, void* d_ws, size_t ws_size,
                              hipStream_t stream) {
    const float* embed      = (const float*)d_in[0];
    const float* action     = (const float*)d_in[1];
    const float* init_deter = (const float*)d_in[3];
    const float* init_stoch = (const float*)d_in[4];
    const float* noise_pr   = (const float*)d_in[5];
    const float* noise_po   = (const float*)d_in[6];
    const float* W_in       = (const float*)d_in[7];
    const float* g_in       = (const float*)d_in[8];
    const float* b_in       = (const float*)d_in[9];
    const float* W_gru      = (const float*)d_in[10];
    const float* g_gru      = (const float*)d_in[11];
    const float* b_gru      = (const float*)d_in[12];
    const float* W_io       = (const float*)d_in[13];
    const float* g_io       = (const float*)d_in[14];
    const float* b_io       = (const float*)d_in[15];
    const float* W_oo       = (const float*)d_in[16];
    const float* g_oo       = (const float*)d_in[17];
    const float* b_oo       = (const float*)d_in[18];
    const float* W_ims      = (const float*)d_in[19];
    const float* b_ims      = (const float*)d_in[20];
    const float* W_obs      = (const float*)d_in[21];
    const float* b_obs      = (const float*)d_in[22];
    float* out = (float*)d_out;

    char* ws = (char*)d_ws;
    size_t off = 0;
    auto alloc = [&](size_t bytes) {
        size_t r = off;
        off = (off + bytes + 255) & ~(size_t)255;
        return r;
    };
    unsigned short* pWgru  = (unsigned short*)(ws + alloc((size_t)GRUK * GRUN * 2));
    unsigned short* pWin_s = (unsigned short*)(ws + alloc((size_t)1024 * 1024 * 2));
    unsigned short* pWin_a = (unsigned short*)(ws + alloc((size_t)128 * 1024 * 2));
    unsigned short* pWio   = (unsigned short*)(ws + alloc((size_t)4096 * 1024 * 2));
    unsigned short* pWood  = (unsigned short*)(ws + alloc((size_t)4096 * 1024 * 2));
    unsigned short* pWooe  = (unsigned short*)(ws + alloc((size_t)1536 * 1024 * 2));
    unsigned short* pWims  = (unsigned short*)(ws + alloc((size_t)1024 * 2048 * 2));
    unsigned short* pWobs  = (unsigned short*)(ws + alloc((size_t)1024 * 2048 * 2));
    unsigned short* act_bf = (unsigned short*)(ws + alloc((size_t)2048 * 128 * 2));
    unsigned short* emb_bf = (unsigned short*)(ws + alloc((size_t)2048 * 1536 * 2));
    float* A_pre  = (float*)(ws + alloc((size_t)2048 * 1024 * 4));
    float* E_pre  = (float*)(ws + alloc((size_t)2048 * 1024 * 4));
    float* x_raw  = (float*)(ws + alloc((size_t)32 * 1024 * 4));
    float* G_raw  = (float*)(ws + alloc((size_t)32 * GRUN * 4));
    float* h_raw  = (float*)(ws + alloc((size_t)32 * 2048 * 4));
    float* deterf = (float*)(ws + alloc((size_t)32 * DETER_ * 4));
    unsigned short* deterb = (unsigned short*)(ws + alloc((size_t)32 * DETER_ * 2));
    unsigned short* stochb = (unsigned short*)(ws + alloc((size_t)32 * 1024 * 2));
    float* px = (float*)(ws + alloc((size_t)16 * 32 * 2 * 4));
    float* pg = (float*)(ws + alloc((size_t)192 * 32 * 2 * 4));
    float* ph = (float*)(ws + alloc((size_t)32 * 32 * 2 * 4));
    (void)ws_size; (void)out_size; (void)n_in; (void)in_sizes;

    auto packgrid = [](long K, long N) { return (unsigned)((K * N / 8 + 255) / 256); };

    // prep: pack weights to bf16 frag-linear
    k_pack<<<packgrid(5120, 12288), 256, 0, stream>>>(W_gru, pWgru, 5120, 12288);
    k_pack<<<packgrid(1024, 1024), 256, 0, stream>>>(W_in, pWin_s, 1024, 1024);
    k_pack<<<packgrid(128, 1024), 256, 0, stream>>>(W_in + (size_t)1024 * 1024, pWin_a, 128, 1024);
    k_pack<<<packgrid(4096, 1024), 256, 0, stream>>>(W_io, pWio, 4096, 1024);
    k_pack<<<packgrid(4096, 1024), 256, 0, stream>>>(W_oo, pWood, 4096, 1024);
    k_pack<<<packgrid(1536, 1024), 256, 0, stream>>>(W_oo + (size_t)4096 * 1024, pWooe, 1536, 1024);
    k_pack<<<packgrid(1024, 2048), 256, 0, stream>>>(W_ims, pWims, 1024, 2048);
    k_pack<<<packgrid(1024, 2048), 256, 0, stream>>>(W_obs, pWobs, 1024, 2048);
    // prep: convert activations / init state
    k_conv<<<(2048 * 128 / 4 + 255) / 256, 256, 0, stream>>>(action, act_bf, 2048L * 128);
    k_conv<<<(2048 * 1536 / 4 + 255) / 256, 256, 0, stream>>>(embed, emb_bf, 2048L * 1536);
    k_conv<<<(32 * 1024 / 4 + 255) / 256, 256, 0, stream>>>(init_stoch, stochb, 32L * 1024);
    k_conv<<<(32 * 4096 / 4 + 255) / 256, 256, 0, stream>>>(init_deter, deterb, 32L * 4096);
    k_copy<<<(32 * 4096 / 4 + 255) / 256, 256, 0, stream>>>(init_deter, deterf, 32L * 4096);
    // prep: time-invariant contributions
    k_prepgemm<<<dim3(16, 64), 256, 0, stream>>>(act_bf, 128, pWin_a, A_pre);
    k_prepgemm<<<dim3(16, 64), 256, 0, stream>>>(emb_bf, 1536, pWooe, E_pre);

    for (int t = 0; t < T_; ++t) {
        k_x<<<16, 256, 0, stream>>>(pWin_s, stochb, A_pre + (size_t)t * 1024, x_raw, px);
        k_gru<<<192, 256, 0, stream>>>(pWgru, x_raw, px, g_in, b_in, deterb, G_raw, pg);
        k_deter<<<128, 256, 0, stream>>>(G_raw, pg, g_gru, b_gru, deterf, deterb, out, t);
        k_h<<<32, 256, 0, stream>>>(pWio, pWood, deterb, E_pre + (size_t)t * 1024, h_raw, ph);
        k_stats<<<64, 256, 0, stream>>>(pWims, pWobs, h_raw, ph, g_io, b_io, g_oo, b_oo,
                                        b_ims, b_obs, noise_pr, noise_po, out, stochb, t);
    }
}